// Round 1
// baseline (344.034 us; speedup 1.0000x reference)
//
#include <hip/hip_runtime.h>

typedef unsigned short u16;
typedef unsigned int u32;
typedef __bf16 bf16x8 __attribute__((ext_vector_type(8)));
typedef float f32x4 __attribute__((ext_vector_type(4)));

#define SCALE 0.125f

// workspace offsets in u16 elements
#define WT_HI_E  ((size_t)0)             // 3 x 1M
#define WT_LO_E  ((size_t)3 << 20)
#define X_HI_E   ((size_t)6 << 20)       // 4M each below
#define X_LO_E   ((size_t)10 << 20)
#define Q_HI_E   ((size_t)14 << 20)
#define Q_LO_E   ((size_t)18 << 20)
#define K_HI_E   ((size_t)22 << 20)
#define K_LO_E   ((size_t)26 << 20)
#define V_HI_E   ((size_t)30 << 20)      // ends at 34M u16 = 68 MB

__device__ __forceinline__ u16 bf16_rne(float x) {
  u32 u = __float_as_uint(x);
  u32 r = (u + 0x7fffu + ((u >> 16) & 1u)) >> 16;
  return (u16)r;
}
__device__ __forceinline__ float bf16_f(u16 h) {
  return __uint_as_float(((u32)h) << 16);
}

// ---------------- X split: fp32 -> bf16 hi/lo ----------------
__global__ __launch_bounds__(256) void k_xsplit(const float* __restrict__ X,
                                                u16* __restrict__ ws) {
  u16* xh = ws + X_HI_E;
  u16* xl = ws + X_LO_E;
  size_t i = ((size_t)blockIdx.x * 256 + threadIdx.x) * 8;
  float4 a = *(const float4*)(X + i);
  float4 b = *(const float4*)(X + i + 4);
  float v[8] = {a.x, a.y, a.z, a.w, b.x, b.y, b.z, b.w};
  u32 Hh[4], Ll[4];
#pragma unroll
  for (int j = 0; j < 4; j++) {
    u16 h0 = bf16_rne(v[2 * j]);
    u16 l0 = bf16_rne(v[2 * j] - bf16_f(h0));
    u16 h1 = bf16_rne(v[2 * j + 1]);
    u16 l1 = bf16_rne(v[2 * j + 1] - bf16_f(h1));
    Hh[j] = (u32)h0 | ((u32)h1 << 16);
    Ll[j] = (u32)l0 | ((u32)l1 << 16);
  }
  *(uint4*)(xh + i) = make_uint4(Hh[0], Hh[1], Hh[2], Hh[3]);
  *(uint4*)(xl + i) = make_uint4(Ll[0], Ll[1], Ll[2], Ll[3]);
}

// ---------------- W transpose + split: W[k][n] -> Wt_hi/lo[n][k] ----------------
__global__ __launch_bounds__(256) void k_wsplit(const float* __restrict__ w0,
                                                const float* __restrict__ w1,
                                                const float* __restrict__ w2,
                                                u16* __restrict__ ws) {
  int z = blockIdx.z;
  const float* W = (z == 0) ? w0 : ((z == 1) ? w1 : w2);
  u16* th = ws + WT_HI_E + (size_t)z * (1u << 20);
  u16* tl = ws + WT_LO_E + (size_t)z * (1u << 20);
  __shared__ float tile[32][33];
  int bx = blockIdx.x * 32, by = blockIdx.y * 32;
  int tx = threadIdx.x & 31, ty = threadIdx.x >> 5;  // 32 x 8
#pragma unroll
  for (int i = 0; i < 4; i++) {
    int r = ty + i * 8;
    tile[r][tx] = W[(size_t)(by + r) * 1024 + bx + tx];
  }
  __syncthreads();
#pragma unroll
  for (int i = 0; i < 4; i++) {
    int r = ty + i * 8;
    float v = tile[tx][r];  // = W[by+tx][bx+r]
    int n = bx + r, k = by + tx;
    u16 h = bf16_rne(v);
    u16 l = bf16_rne(v - bf16_f(h));
    th[(size_t)n * 1024 + k] = h;
    tl[(size_t)n * 1024 + k] = l;
  }
}

// ---------------- projections: Y = X @ W, compensated bf16 MFMA ----------------
// z=0 -> Q (hi+lo), z=1 -> K (hi+lo), z=2 -> V (hi only). Output layout [h*2+b][s][d].
__global__ __launch_bounds__(256) void k_proj(u16* __restrict__ ws) {
  int z = blockIdx.z;
  const u16* Xh = ws + X_HI_E;
  const u16* Xl = ws + X_LO_E;
  const u16* Wh = ws + WT_HI_E + (size_t)z * (1u << 20);
  const u16* Wl = ws + WT_LO_E + (size_t)z * (1u << 20);
  u16* dsth = ws + ((z == 0) ? Q_HI_E : ((z == 1) ? K_HI_E : V_HI_E));
  u16* dstl = (z == 0) ? (ws + Q_LO_E) : ((z == 1) ? (ws + K_LO_E) : (u16*)0);

  __shared__ u16 sXh[128][32], sXl[128][32], sWh[128][32], sWl[128][32];
  int M0 = blockIdx.y * 128, N0 = blockIdx.x * 128;
  int tid = threadIdx.x, lane = tid & 63, w = tid >> 6;
  int quad = lane >> 4, l16 = lane & 15;
  int mb = (w & 1) * 64, nb = (w >> 1) * 64;

  const f32x4 z4 = {0.f, 0.f, 0.f, 0.f};
  f32x4 acc[4][4];
#pragma unroll
  for (int i = 0; i < 4; i++)
#pragma unroll
    for (int j = 0; j < 4; j++) acc[i][j] = z4;

  for (int kk = 0; kk < 1024; kk += 32) {
    __syncthreads();
    // stage: 4 arrays x 128 rows x 4 uint4-chunks = 2048 chunks
#pragma unroll
    for (int c0 = 0; c0 < 2048; c0 += 256) {
      int c = c0 + tid;
      int sel = c >> 10, rem = c & 1023, a = rem >> 9, r2 = rem & 511;
      int row = r2 >> 2, q8 = r2 & 3;
      const u16* src = sel ? (a ? Wl : Wh) : (a ? Xl : Xh);
      size_t g = sel ? ((size_t)(N0 + row) * 1024 + kk + q8 * 8)
                     : ((size_t)(M0 + row) * 1024 + kk + q8 * 8);
      uint4 v = *(const uint4*)(src + g);
      u16* d = sel ? (a ? &sWl[row][q8 * 8] : &sWh[row][q8 * 8])
                   : (a ? &sXl[row][q8 * 8] : &sXh[row][q8 * 8]);
      *(uint4*)d = v;
    }
    __syncthreads();
    bf16x8 ah[4], al[4], bh[4], bl[4];
#pragma unroll
    for (int i = 0; i < 4; i++) {
      ah[i] = *(const bf16x8*)&sXh[mb + i * 16 + l16][quad * 8];
      al[i] = *(const bf16x8*)&sXl[mb + i * 16 + l16][quad * 8];
      bh[i] = *(const bf16x8*)&sWh[nb + i * 16 + l16][quad * 8];
      bl[i] = *(const bf16x8*)&sWl[nb + i * 16 + l16][quad * 8];
    }
#pragma unroll
    for (int i = 0; i < 4; i++)
#pragma unroll
      for (int j = 0; j < 4; j++) {
        f32x4 c0 = acc[i][j];
        c0 = __builtin_amdgcn_mfma_f32_16x16x32_bf16(ah[i], bh[j], c0, 0, 0, 0);
        c0 = __builtin_amdgcn_mfma_f32_16x16x32_bf16(ah[i], bl[j], c0, 0, 0, 0);
        c0 = __builtin_amdgcn_mfma_f32_16x16x32_bf16(al[i], bh[j], c0, 0, 0, 0);
        acc[i][j] = c0;
      }
  }
#pragma unroll
  for (int i = 0; i < 4; i++)
#pragma unroll
    for (int j = 0; j < 4; j++)
#pragma unroll
      for (int r = 0; r < 4; r++) {
        int mg = M0 + mb + i * 16 + quad * 4 + r;
        int ng = N0 + nb + j * 16 + l16;
        int b = mg >> 11, s = mg & 2047;
        int hh = ng >> 6, d = ng & 63;
        size_t idx = ((size_t)(hh * 2 + b) * 2048 + s) * 64 + d;
        float y = acc[i][j][r];
        u16 h = bf16_rne(y);
        dsth[idx] = h;
        if (dstl) dstl[idx] = bf16_rne(y - bf16_f(h));
      }
}

// ---------------- flash attention ----------------
// BQ=128 (4 waves x 32 rows), BK=64 keys/iter. Compensated scores, online softmax.
__global__ __launch_bounds__(256) void k_attn(const u16* __restrict__ ws,
                                              float* __restrict__ out) {
  const u16* Qh = ws + Q_HI_E;
  const u16* Ql = ws + Q_LO_E;
  const u16* Kh = ws + K_HI_E;
  const u16* Kl = ws + K_LO_E;
  const u16* Vv = ws + V_HI_E;

  __shared__ u16 sKh[64][72], sKl[64][72], sVt[64][72];
  __shared__ u16 sP[4][32][72];

  int hb = blockIdx.y;
  int q0 = blockIdx.x * 128;
  int tid = threadIdx.x, w = tid >> 6, lane = tid & 63;
  int quad = lane >> 4, l16 = lane & 15;
  size_t base = (size_t)hb * (2048 * 64);

  bf16x8 qh[2][2], ql[2][2];
#pragma unroll
  for (int mt = 0; mt < 2; mt++)
#pragma unroll
    for (int kc = 0; kc < 2; kc++) {
      size_t off = base + (size_t)(q0 + w * 32 + mt * 16 + l16) * 64 + kc * 32 + quad * 8;
      qh[mt][kc] = *(const bf16x8*)(Qh + off);
      ql[mt][kc] = *(const bf16x8*)(Ql + off);
    }
  const f32x4 z4 = {0.f, 0.f, 0.f, 0.f};
  float mr[2][4], lr[2][4];
  f32x4 o[2][4];
#pragma unroll
  for (int a = 0; a < 2; a++)
#pragma unroll
    for (int b = 0; b < 4; b++) o[a][b] = z4;
#pragma unroll
  for (int a = 0; a < 2; a++)
#pragma unroll
    for (int r = 0; r < 4; r++) {
      mr[a][r] = -1e30f;
      lr[a][r] = 0.f;
    }

  for (int kt = 0; kt < 2048; kt += 64) {
    __syncthreads();
    // stage K hi/lo: 2 arrays x 64 rows x 8 uint4-chunks = 1024
#pragma unroll
    for (int c0 = 0; c0 < 1024; c0 += 256) {
      int c = c0 + tid;
      int a = c >> 9, rem = c & 511, row = rem >> 3, q8 = rem & 7;
      const u16* src = (a ? Kl : Kh) + base + (size_t)(kt + row) * 64 + q8 * 8;
      uint4 v = *(const uint4*)src;
      if (a)
        *(uint4*)&sKl[row][q8 * 8] = v;
      else
        *(uint4*)&sKh[row][q8 * 8] = v;
    }
    // stage V transposed: sVt[d][key]
#pragma unroll
    for (int c0 = 0; c0 < 1024; c0 += 256) {
      int c = c0 + tid;
      int key = c >> 4, d4 = c & 15;
      uint2 v = *(const uint2*)(Vv + base + (size_t)(kt + key) * 64 + d4 * 4);
      sVt[d4 * 4 + 0][key] = (u16)(v.x & 0xffffu);
      sVt[d4 * 4 + 1][key] = (u16)(v.x >> 16);
      sVt[d4 * 4 + 2][key] = (u16)(v.y & 0xffffu);
      sVt[d4 * 4 + 3][key] = (u16)(v.y >> 16);
    }
    __syncthreads();

    bf16x8 kh[4][2], klo[4][2];
#pragma unroll
    for (int nt = 0; nt < 4; nt++)
#pragma unroll
      for (int kc = 0; kc < 2; kc++) {
        kh[nt][kc] = *(const bf16x8*)&sKh[nt * 16 + l16][kc * 32 + quad * 8];
        klo[nt][kc] = *(const bf16x8*)&sKl[nt * 16 + l16][kc * 32 + quad * 8];
      }
    f32x4 sc[2][4];
#pragma unroll
    for (int mt = 0; mt < 2; mt++)
#pragma unroll
      for (int nt = 0; nt < 4; nt++) {
        f32x4 a = z4;
#pragma unroll
        for (int kc = 0; kc < 2; kc++) {
          a = __builtin_amdgcn_mfma_f32_16x16x32_bf16(qh[mt][kc], kh[nt][kc], a, 0, 0, 0);
          a = __builtin_amdgcn_mfma_f32_16x16x32_bf16(qh[mt][kc], klo[nt][kc], a, 0, 0, 0);
          a = __builtin_amdgcn_mfma_f32_16x16x32_bf16(ql[mt][kc], kh[nt][kc], a, 0, 0, 0);
        }
        sc[mt][nt] = a;
      }
    // online softmax (rows = quad*4 + r within each 16-row tile)
#pragma unroll
    for (int mt = 0; mt < 2; mt++) {
#pragma unroll
      for (int r = 0; r < 4; r++) {
        float m1 = fmaxf(fmaxf(sc[mt][0][r], sc[mt][1][r]),
                         fmaxf(sc[mt][2][r], sc[mt][3][r])) * SCALE;
#pragma unroll
        for (int off = 1; off < 16; off <<= 1) m1 = fmaxf(m1, __shfl_xor(m1, off));
        float mnew = fmaxf(mr[mt][r], m1);
        float alpha = __expf(mr[mt][r] - mnew);
        mr[mt][r] = mnew;
        float rs = 0.f;
#pragma unroll
        for (int nt = 0; nt < 4; nt++) {
          float p = __expf(sc[mt][nt][r] * SCALE - mnew);
          rs += p;
          sP[w][mt * 16 + quad * 4 + r][nt * 16 + l16] = bf16_rne(p);
        }
#pragma unroll
        for (int off = 1; off < 16; off <<= 1) rs += __shfl_xor(rs, off);
        lr[mt][r] = lr[mt][r] * alpha + rs;
#pragma unroll
        for (int dn = 0; dn < 4; dn++) o[mt][dn][r] *= alpha;
      }
    }
    // P @ V
    bf16x8 vb[4][2], pa[2][2];
#pragma unroll
    for (int dn = 0; dn < 4; dn++)
#pragma unroll
      for (int kc = 0; kc < 2; kc++)
        vb[dn][kc] = *(const bf16x8*)&sVt[dn * 16 + l16][kc * 32 + quad * 8];
#pragma unroll
    for (int mt = 0; mt < 2; mt++)
#pragma unroll
      for (int kc = 0; kc < 2; kc++)
        pa[mt][kc] = *(const bf16x8*)&sP[w][mt * 16 + l16][kc * 32 + quad * 8];
#pragma unroll
    for (int mt = 0; mt < 2; mt++)
#pragma unroll
      for (int dn = 0; dn < 4; dn++) {
        f32x4 a = o[mt][dn];
        a = __builtin_amdgcn_mfma_f32_16x16x32_bf16(pa[mt][0], vb[dn][0], a, 0, 0, 0);
        a = __builtin_amdgcn_mfma_f32_16x16x32_bf16(pa[mt][1], vb[dn][1], a, 0, 0, 0);
        o[mt][dn] = a;
      }
  }
#pragma unroll
  for (int mt = 0; mt < 2; mt++)
#pragma unroll
    for (int dn = 0; dn < 4; dn++)
#pragma unroll
      for (int r = 0; r < 4; r++) {
        int row = q0 + w * 32 + mt * 16 + quad * 4 + r;
        out[((size_t)hb * 2048 + row) * 64 + dn * 16 + l16] = o[mt][dn][r] / lr[mt][r];
      }
}

extern "C" void kernel_launch(void* const* d_in, const int* in_sizes, int n_in,
                              void* d_out, int out_size, void* d_ws, size_t ws_size,
                              hipStream_t stream) {
  const float* X = (const float*)d_in[0];
  const float* Wq = (const float*)d_in[1];
  const float* Wk = (const float*)d_in[2];
  const float* Wv = (const float*)d_in[3];
  u16* ws = (u16*)d_ws;
  float* out = (float*)d_out;

  k_xsplit<<<dim3(2048), dim3(256), 0, stream>>>(X, ws);
  k_wsplit<<<dim3(32, 32, 3), dim3(256), 0, stream>>>(Wq, Wk, Wv, ws);
  k_proj<<<dim3(8, 32, 3), dim3(256), 0, stream>>>(ws);
  k_attn<<<dim3(16, 32), dim3(256), 0, stream>>>(ws, out);
}